// Round 8
// baseline (200.893 us; speedup 1.0000x reference)
//
#include <hip/hip_runtime.h>
#include <math.h>

#define NH 12
#define HD 64
#define NSEQ 1024
#define BATCH 8
#define EMB 768
#define NQKV 2304
#define MROWS 8192   // B*N

typedef _Float16 half8 __attribute__((ext_vector_type(8)));
typedef _Float16 half4 __attribute__((ext_vector_type(4)));
typedef _Float16 half2v __attribute__((ext_vector_type(2)));
typedef __fp16 fp16x2 __attribute__((ext_vector_type(2)));   // cvt_pkrtz ret type
typedef float f32x4 __attribute__((ext_vector_type(4)));
typedef float f32x16 __attribute__((ext_vector_type(16)));
typedef unsigned int u32;

#define MFMA16(a,b,c) __builtin_amdgcn_mfma_f32_16x16x32_f16(a, b, c, 0, 0, 0)
#define MFMA32(a,b,c) __builtin_amdgcn_mfma_f32_32x32x16_f16(a, b, c, 0, 0, 0)

// q pre-scale folds softmax's log2(e): 0.125 * 1.4426950408889634
#define QSCALE 0.18033688011112043f
// exp bias: 4 * log2(e)  (p = 2^(s*0.125*log2e - 5.7708) == e^(s*0.125 - 4))
#define EXPB 5.770780163555856f

// async global->LDS, 16B per lane; LDS dest is wave-uniform base + lane*16.
#define ASYNC16(g, l)                                                          \
  __builtin_amdgcn_global_load_lds(                                            \
      (const __attribute__((address_space(1))) unsigned int*)(g),              \
      (__attribute__((address_space(3))) unsigned int*)(l), 16, 0, 0)

// ---------------------------------------------------------------------------
// Fused prepass: [0,6144) f32->f16 convert of x; [6144,6576) transpose+cvt
// w_qkv; [6576,6720) transpose+cvt w_proj. One launch.
// ---------------------------------------------------------------------------
__device__ __forceinline__ void transpose_tile(const float* __restrict__ in,
                                               _Float16* __restrict__ out,
                                               int R, int C, int bx, int by,
                                               _Float16 (*T)[72]) {
  const int tr = by * 64, tc = bx * 64;
  const int r = threadIdx.x >> 2, s = threadIdx.x & 3;
  const float* src = in + (size_t)(tr + r) * C + tc + s * 16;
  _Float16* dst = &T[r][s * 16];
  #pragma unroll
  for (int i = 0; i < 4; ++i) {
    float4 v = ((const float4*)src)[i];
    dst[4*i+0] = (_Float16)v.x; dst[4*i+1] = (_Float16)v.y;
    dst[4*i+2] = (_Float16)v.z; dst[4*i+3] = (_Float16)v.w;
  }
  __syncthreads();
  alignas(16) _Float16 tmp[16];
  #pragma unroll
  for (int j = 0; j < 16; ++j) tmp[j] = T[s * 16 + j][r];
  half8* o = (half8*)(out + (size_t)(tc + r) * R + tr + s * 16);
  o[0] = *(half8*)&tmp[0];
  o[1] = *(half8*)&tmp[8];
}

__global__ __launch_bounds__(256) void prepass(const float* __restrict__ x,
                                               _Float16* __restrict__ xh,
                                               const float* __restrict__ wq,
                                               _Float16* __restrict__ wqT,
                                               const float* __restrict__ wp,
                                               _Float16* __restrict__ wpT) {
  __shared__ _Float16 T[64][72];
  const int bid = blockIdx.x;
  if (bid < 6144) {
    int i = bid * 256 + threadIdx.x;            // n4 = 8192*768/4 = 1572864
    float4 v = ((const float4*)x)[i];
    half4 h = { (_Float16)v.x, (_Float16)v.y, (_Float16)v.z, (_Float16)v.w };
    ((half4*)xh)[i] = h;
  } else if (bid < 6576) {
    int idx = bid - 6144;                        // 36 x 12
    transpose_tile(wq, wqT, EMB, NQKV, idx % 36, idx / 36, T);
  } else {
    int idx = bid - 6576;                        // 12 x 12
    transpose_tile(wp, wpT, EMB, EMB, idx % 12, idx / 12, T);
  }
}

// XCD-aware bijective tile remap (nwg % 8 == 0): default dispatch
// round-robins flat ids over the 8 XCDs; remapping to (f%8)*(nwg/8) + f/8
// gives each XCD a contiguous tile range -> shared operand panels stay
// L2-resident per XCD. (R4: QKV FETCH 63.7->34.7 MB.)
__device__ __forceinline__ int xcd_remap() {
  const int flat = blockIdx.y * gridDim.x + blockIdx.x;
  const int q = (gridDim.x * gridDim.y) >> 3;
  return (flat & 7) * q + (flat >> 3);
}

// ---------------------------------------------------------------------------
// QKV GEMM, 128x128 tile, 256 threads (4 waves, 2x2), BK=32, dbuf.
// EXACT R5 SCHEDULE (measured floor 54.5 µs; six variants — reg-staged,
// counted-vmcnt tbuf, f32-A fusion, persistent grid, bf-streaming — all
// neutral or worse). ASYNC-STAGED (global_load_lds width 16) pipelined
// K-loop. LDS dest LINEAR; XOR image LDS[r][s] = G[r][s ^ ((r>>1)&3)] via
// PRE-SWIZZLED global source seg; frag reads conflict-free
// (xq = quad ^ ((l15>>1)&3)). A [M][K] k-contig, BT [N][K] k-contig.
// Epilogue: bias + RoPE (pos = head!) + q*QSCALE (0.125*log2e, folding
//           softmax's exp2); q,k [bh][n][d] f16, v TRANSPOSED [bh][d][n]
//           f16 with keys sigma-permuted (bits 2<->3) so attention needs
//           no P lane-exchange.
// ---------------------------------------------------------------------------
__global__ __launch_bounds__(256) void gemm_qkv(const _Float16* __restrict__ A,
                                                const _Float16* __restrict__ BT,
                                                const float* __restrict__ bias,
                                                _Float16* __restrict__ qo,
                                                _Float16* __restrict__ ko,
                                                _Float16* __restrict__ vo,
                                                int K) {
  const int BUFH = 128 * 32;
  __shared__ __align__(16) _Float16 As[2 * 128 * 32];   // [buf][m][k] pitch 32
  __shared__ __align__(16) _Float16 Bs[2 * 128 * 32];   // [buf][n][k] pitch 32
  const int tid = threadIdx.x;
  const int lane = tid & 63, wave = tid >> 6;
  const int quad = lane >> 4, l15 = lane & 15;
  const int wm = (wave >> 1) * 64, wn = (wave & 1) * 64;
  const int nf = xcd_remap();
  const int row0 = (nf / gridDim.x) * 128, col0 = (nf % gridDim.x) * 128;

  // staging: wave w covers rows [w*32, w*32+32) of A and B, two 16-row
  // batches of 1024B each.  Lane l -> dest row l>>2, dest seg l&3 (linear);
  // source seg is XOR-swizzled so the LDS image matches the frag reads.
  const int srow = lane >> 2;
  const int sseg = (lane & 3) ^ ((srow >> 1) & 3);   // pre-swizzled src seg
  const _Float16* gA = A + (size_t)(row0 + wave*32 + srow) * K + sseg * 8;
  const _Float16* gB = BT + (size_t)(col0 + wave*32 + srow) * K + sseg * 8;
  _Float16* lA = As + (wave * 32) * 32;              // wave-uniform LDS base
  _Float16* lB = Bs + (wave * 32) * 32;

  // frag-read swizzled col (lane constant: (row>>1)&3 == (l15>>1)&3)
  const int xq = (quad ^ ((l15 >> 1) & 3)) * 8;

  f32x4 acc[4][4];
  #pragma unroll
  for (int i = 0; i < 4; ++i)
    #pragma unroll
    for (int j = 0; j < 4; ++j) {
      f32x4 z = {0.f, 0.f, 0.f, 0.f};
      acc[i][j] = z;
    }

  // prologue: stage k0=0 into buf 0 (4 x global_load_lds_dwordx4 per wave)
  ASYNC16(gA,          lA);
  ASYNC16(gA + 16 * K, lA + 16*32);
  ASYNC16(gB,          lB);
  ASYNC16(gB + 16 * K, lB + 16*32);
  __syncthreads();

  int buf = 0;
  for (int k0 = 0; k0 < K; k0 += 32) {
    if (k0 + 32 < K) {               // issue next-stage direct-to-LDS loads
      const int nb = (buf ^ 1) * BUFH;        //  (latency hidden behind MFMAs)
      ASYNC16(gA + k0 + 32,          lA + nb);
      ASYNC16(gA + k0 + 32 + 16 * K, lA + nb + 16*32);
      ASYNC16(gB + k0 + 32,          lB + nb);
      ASYNC16(gB + k0 + 32 + 16 * K, lB + nb + 16*32);
    }
    const _Float16* Ab = As + buf * BUFH;
    const _Float16* Bb = Bs + buf * BUFH;
    half8 af[4], bf[4];
    #pragma unroll
    for (int mt = 0; mt < 4; ++mt)
      af[mt] = *(const half8*)(Ab + (wm + mt*16 + l15) * 32 + xq);
    #pragma unroll
    for (int nt = 0; nt < 4; ++nt)
      bf[nt] = *(const half8*)(Bb + (wn + nt*16 + l15) * 32 + xq);
    #pragma unroll
    for (int mt = 0; mt < 4; ++mt)
      #pragma unroll
      for (int nt = 0; nt < 4; ++nt)
        acc[mt][nt] = MFMA16(af[mt], bf[nt], acc[mt][nt]);
    __syncthreads();                 // drains vmcnt -> buf^1 ready
    buf ^= 1;
  }

  float bcol[4];
  #pragma unroll
  for (int nt = 0; nt < 4; ++nt)
    bcol[nt] = bias[col0 + wn + nt*16 + l15];

  const int ch = col0 + wn;           // multiple of 64 -> single (t, h)
  const int tt = ch / EMB;
  const int hh = (ch % EMB) >> 6;
  float cs[2], sn[2];
  if (tt < 2) {
    #pragma unroll
    for (int j = 0; j < 2; ++j) {
      float fi = (float)(j*16 + l15);
      float ang = (float)hh * expf(-0.28782313662425574f * fi);
      sincosf(ang, &sn[j], &cs[j]);
    }
  }
  #pragma unroll
  for (int mt = 0; mt < 4; ++mt) {
    int m0 = row0 + wm + mt*16 + quad*4;
    int b = m0 >> 10, n0 = m0 & 1023;
    size_t bh = (size_t)(b * NH + hh);
    if (tt == 2) {
      // sigma-permuted key position (swap bits 2<->3; n0 multiple of 4)
      int np = (n0 & ~12) | ((n0 & 4) << 1) | ((n0 & 8) >> 1);
      #pragma unroll
      for (int nt = 0; nt < 4; ++nt) {
        int d = nt*16 + l15;
        half4 pk;
        #pragma unroll
        for (int r = 0; r < 4; ++r)
          pk[r] = (_Float16)(acc[mt][nt][r] + bcol[nt]);
        *(half4*)(vo + (bh * HD + d) * NSEQ + np) = pk;
      }
    } else {
      _Float16* dst = (tt == 0) ? qo : ko;
      const float sc = (tt == 0) ? QSCALE : 1.0f;
      #pragma unroll
      for (int j = 0; j < 2; ++j) {
        #pragma unroll
        for (int r = 0; r < 4; ++r) {
          float lo = acc[mt][j][r]     + bcol[j];
          float hi = acc[mt][j + 2][r] + bcol[j + 2];
          float nlo = (lo * cs[j] - hi * sn[j]) * sc;
          float nhi = (hi * cs[j] + lo * sn[j]) * sc;
          size_t rowoff = (bh * NSEQ + (size_t)(n0 + r)) * HD;
          dst[rowoff + j*16 + l15]      = (_Float16)nlo;
          dst[rowoff + j*16 + l15 + 32] = (_Float16)nhi;
        }
      }
    }
  }
}

// ---------------------------------------------------------------------------
// Proj GEMM, 128x64 tile -> 768 blocks = 3 blocks/CU, 4 waves 2x2 over
// (128,64), BK=32, dbuf, all-async staging with pre-swizzled global source.
// out f32 = acc + bias.
// ---------------------------------------------------------------------------
__global__ __launch_bounds__(256) void gemm_proj(const _Float16* __restrict__ A,
                                                 const _Float16* __restrict__ BT,
                                                 const float* __restrict__ bias,
                                                 float* __restrict__ outf,
                                                 int K) {
  const int ABUF = 128 * 32, BBUF = 64 * 32;
  __shared__ __align__(16) _Float16 As[2 * ABUF];   // [buf][m][k] pitch 32
  __shared__ __align__(16) _Float16 Bs[2 * BBUF];   // [buf][n][k] pitch 32
  const int tid = threadIdx.x;
  const int lane = tid & 63, wave = tid >> 6;
  const int quad = lane >> 4, l15 = lane & 15;
  const int wm = (wave >> 1) * 64, wn = (wave & 1) * 32;
  const int nf = xcd_remap();
  const int row0 = (nf / gridDim.x) * 128, col0 = (nf % gridDim.x) * 64;

  const int srow = lane >> 2;                        // 0..15
  const int sseg = (lane & 3) ^ ((srow >> 1) & 3);   // pre-swizzled source
  const _Float16* gA = A  + (size_t)(row0 + wave*32 + srow) * K + sseg * 8;
  const _Float16* gB = BT + (size_t)(col0 + wave*16 + srow) * K + sseg * 8;
  _Float16* lA = As + (wave * 32) * 32;              // linear async dests
  _Float16* lB = Bs + (wave * 16) * 32;

  const int xq = (quad ^ ((l15 >> 1) & 3)) * 8;

  f32x4 acc[4][2];
  #pragma unroll
  for (int i = 0; i < 4; ++i)
    #pragma unroll
    for (int j = 0; j < 2; ++j) {
      f32x4 z = {0.f, 0.f, 0.f, 0.f};
      acc[i][j] = z;
    }

  // prologue: stage tile 0 into buf 0 (A: 2 batches; B: 1 batch)
  ASYNC16(gA,          lA);
  ASYNC16(gA + 16 * K, lA + 16*32);
  ASYNC16(gB,          lB);
  __syncthreads();

  int buf = 0;
  for (int k0 = 0; k0 < K; k0 += 32) {
    if (k0 + 32 < K) {
      ASYNC16(gA + k0 + 32,          lA + (buf ^ 1) * ABUF);
      ASYNC16(gA + k0 + 32 + 16 * K, lA + (buf ^ 1) * ABUF + 16*32);
      ASYNC16(gB + k0 + 32,          lB + (buf ^ 1) * BBUF);
    }
    const _Float16* Ab = As + buf * ABUF;
    const _Float16* Bb = Bs + buf * BBUF;
    half8 af[4], bf[2];
    #pragma unroll
    for (int mt = 0; mt < 4; ++mt)
      af[mt] = *(const half8*)(Ab + (wm + mt*16 + l15) * 32 + xq);
    #pragma unroll
    for (int nt = 0; nt < 2; ++nt)
      bf[nt] = *(const half8*)(Bb + (wn + nt*16 + l15) * 32 + xq);
    #pragma unroll
    for (int mt = 0; mt < 4; ++mt)
      #pragma unroll
      for (int nt = 0; nt < 2; ++nt)
        acc[mt][nt] = MFMA16(af[mt], bf[nt], acc[mt][nt]);
    __syncthreads();
    buf ^= 1;
  }

  float bcol[2];
  #pragma unroll
  for (int nt = 0; nt < 2; ++nt)
    bcol[nt] = bias[col0 + wn + nt*16 + l15];
  #pragma unroll
  for (int mt = 0; mt < 4; ++mt) {
    int m0 = row0 + wm + mt*16 + quad*4;
    #pragma unroll
    for (int nt = 0; nt < 2; ++nt)
      #pragma unroll
      for (int r = 0; r < 4; ++r)
        outf[(size_t)(m0 + r) * EMB + col0 + wn + nt*16 + l15] =
            acc[mt][nt][r] + bcol[nt];
  }
}

// ---------------------------------------------------------------------------
// f16 MFMA flash attention, 32x32x16, ASYNC-STAGED pipelined K/V chunks:
// global_load_lds (width 16) issues next chunk's loads into buf^1 at loop
// top; the bottom __syncthreads drains vmcnt. LDS dest LINEAR; the image
// LDS[r][s] = G[r][s ^ (r&7)] comes from PRE-SWIZZLING the global source
// segment (seg' = sseg8 ^ (srow8&7)). Static softmax p = 2^(s - EXPB)
// (q pre-scaled by 0.125*log2e; shift cancels in normalization), packed to
// f16 via cvt_pkrtz (1 op vs 3). V keys sigma-permuted by the QKV epilogue
// so S^T C-regs ARE the PV B-fragment. s_setprio(1) wraps both MFMA
// clusters (T5). Block = 256 thr (4 waves) = 128 queries; chunk = 64 keys
// shared by waves. XCD remap: each XCD owns 12 complete bh groups.
// q,k: [bh][n][d] f16. vt: [bh][d][key_sigma] f16. Output ao: [B*N][EMB] f16.
// ---------------------------------------------------------------------------
__global__ __launch_bounds__(256) void attn_mfma32(const _Float16* __restrict__ q,
                                                   const _Float16* __restrict__ k,
                                                   const _Float16* __restrict__ vt,
                                                   _Float16* __restrict__ ao) {
  const int BUFH = 64 * 64;
  __shared__ __align__(16) _Float16 Ks[2 * 64 * 64];   // [buf][key][slot*8]
  __shared__ __align__(16) _Float16 Vs[2 * 64 * 64];   // [buf][d][slot*8]
  const int tid = threadIdx.x;
  const int lane = tid & 63, wave = tid >> 6;
  const int l31 = lane & 31, hi = lane >> 5;
  const int nf = xcd_remap();                    // grid (8, 96), 768 % 8 == 0
  const int bh = nf >> 3;
  const int qrow = (nf & 7) * 128 + wave * 32 + l31;     // global query idx
  const size_t base = (size_t)bh * NSEQ * HD;

  // Q fragments (B-operand: [n=query][k=d]) in registers for all chunks
  const _Float16* qp = q + base + (size_t)qrow * HD + hi * 8;
  half8 qf[4];
  #pragma unroll
  for (int kh = 0; kh < 4; ++kh)
    qf[kh] = *(const half8*)(qp + kh * 16);

  // staging: wave covers rows wave*16..+15 (batches srow8, srow8+8).
  // Lane l -> LINEAR dest (row l>>3, seg l&7 from wave base); global source
  // seg pre-swizzled so LDS image is LDS[r][s] = G[r][s ^ (r&7)].
  const int srow8 = lane >> 3;                    // 0..7
  const int sseg8 = lane & 7;
  const int wseg8 = sseg8 ^ (srow8 & 7);          // pre-swizzled src seg
  const _Float16* kg = k + base + (size_t)(wave*16 + srow8) * HD + wseg8 * 8;
  const _Float16* vg = vt + (size_t)bh * HD * NSEQ
                       + (size_t)(wave*16 + srow8) * NSEQ + wseg8 * 8;
  _Float16* uK = Ks + (wave * 16) * 64;           // wave-uniform LDS bases
  _Float16* uV = Vs + (wave * 16) * 64;

  // frag-read swizzled offsets (halves): slot = (kh*2+hi) ^ (l31&7)
  int xofs[4];
  #pragma unroll
  for (int kh = 0; kh < 4; ++kh)
    xofs[kh] = ((kh*2 + hi) ^ (l31 & 7)) * 8;

  f32x16 O[2];
  #pragma unroll
  for (int dt = 0; dt < 2; ++dt)
    #pragma unroll
    for (int r = 0; r < 16; ++r) O[dt][r] = 0.f;
  float l = 0.f;

  // prologue: stage chunk 0 into buf 0 (4 x global_load_lds_dwordx4)
  ASYNC16(kg,              uK);
  ASYNC16(kg + 8 * HD,     uK + 8*64);
  ASYNC16(vg,              uV);
  ASYNC16(vg + 8 * NSEQ,   uV + 8*64);
  __syncthreads();

  int buf = 0;
  for (int c0 = 0; c0 < NSEQ; c0 += 64) {
    if (c0 + 64 < NSEQ) {          // next chunk's loads, hidden behind compute
      const int nb = (buf ^ 1) * BUFH;
      const _Float16* kc = kg + (size_t)(c0 + 64) * HD;
      ASYNC16(kc,                  uK + nb);
      ASYNC16(kc + 8 * HD,         uK + nb + 8*64);
      ASYNC16(vg + c0 + 64,        uV + nb);
      ASYNC16(vg + 8*NSEQ + c0 + 64, uV + nb + 8*64);
    }
    const _Float16* Kb = Ks + buf * BUFH;
    const _Float16* Vb = Vs + buf * BUFH;

    // ---- S^T = K Q^T : 2 key-tiles of 32, K=16 per MFMA over D=64 ----
    f32x16 ct[2];
    __builtin_amdgcn_s_setprio(1);
    #pragma unroll
    for (int kt = 0; kt < 2; ++kt) {
      #pragma unroll
      for (int r = 0; r < 16; ++r) ct[kt][r] = 0.f;
      #pragma unroll
      for (int kh = 0; kh < 4; ++kh) {
        half8 kf = *(const half8*)(Kb + (kt*32 + l31) * 64 + xofs[kh]);
        ct[kt] = MFMA32(kf, qf[kh], ct[kt]);
      }
    }
    __builtin_amdgcn_s_setprio(0);

    // ---- static softmax: p = 2^(s - EXPB), per-lane partial l ----
    union { half2v v; fp16x2 f; int i; } ph2[16];
    float rs = 0.f;
    #pragma unroll
    for (int kt = 0; kt < 2; ++kt)
      #pragma unroll
      for (int rp = 0; rp < 8; ++rp) {
        float p0 = __builtin_amdgcn_exp2f(ct[kt][2*rp]     - EXPB);
        float p1 = __builtin_amdgcn_exp2f(ct[kt][2*rp + 1] - EXPB);
        rs += p0 + p1;
        ph2[kt*8 + rp].f = __builtin_amdgcn_cvt_pkrtz(p0, p1);
      }
    l += rs;

    // ---- O^T += V^T P^T : P^T B-frag = C-regs directly (V sigma-perm) ----
    __builtin_amdgcn_s_setprio(1);
    #pragma unroll
    for (int kh = 0; kh < 4; ++kh) {
      const int kt = kh >> 1;
      const int iA = kt*8 + (kh & 1)*4;
      union { half8 h; int d[4]; } pf;
      pf.d[0] = ph2[iA].i;     pf.d[1] = ph2[iA + 1].i;
      pf.d[2] = ph2[iA + 2].i; pf.d[3] = ph2[iA + 3].i;
      #pragma unroll
      for (int dt = 0; dt < 2; ++dt) {
        half8 vf = *(const half8*)(Vb + (dt*32 + l31) * 64 + xofs[kh]);
        O[dt] = MFMA32(vf, pf.h, O[dt]);
      }
    }
    __builtin_amdgcn_s_setprio(0);

    __syncthreads();               // drains vmcnt -> buf^1 ready
    buf ^= 1;
  }

  // each lane's l covers its 32 score regs; xor-32 partner holds the rest
  l += __shfl_xor(l, 32);

  // ---- write O^T (col=query=lane&31, rows=d) to ao[B*N][EMB] ----
  const int b = bh / NH, hh = bh % NH;
  const float inv = 1.0f / l;
  _Float16* orow = ao + (size_t)(b * NSEQ + qrow) * EMB + hh * HD;
  #pragma unroll
  for (int dt = 0; dt < 2; ++dt)
    #pragma unroll
    for (int t = 0; t < 4; ++t) {
      int d0 = dt*32 + 8*t + 4*hi;          // rows (r&3)+8*(r>>2)+4*hi
      half4 o4;
      #pragma unroll
      for (int j = 0; j < 4; ++j)
        o4[j] = (_Float16)(O[dt][4*t + j] * inv);
      *(half4*)(orow + d0) = o4;
    }
}

// ---------------------------------------------------------------------------
extern "C" void kernel_launch(void* const* d_in, const int* in_sizes, int n_in,
                              void* d_out, int out_size, void* d_ws, size_t ws_size,
                              hipStream_t stream) {
  const float* x      = (const float*)d_in[0];
  const float* w_qkv  = (const float*)d_in[1];
  const float* b_qkv  = (const float*)d_in[2];
  const float* w_proj = (const float*)d_in[3];
  const float* b_proj = (const float*)d_in[4];
  float* out = (float*)d_out;

  _Float16* xh  = (_Float16*)d_ws;                 // [8192][768]
  _Float16* wqT = xh  + (size_t)MROWS * EMB;       // [2304][768]
  _Float16* wpT = wqT + (size_t)NQKV * EMB;        // [768][768]
  _Float16* qh  = wpT + (size_t)EMB * EMB;         // [96][1024][64]
  _Float16* kh  = qh  + (size_t)BATCH*NH*NSEQ*HD;
  _Float16* vth = kh  + (size_t)BATCH*NH*NSEQ*HD;  // [96][64][1024] sigma-perm
  _Float16* aoh = vth + (size_t)BATCH*NH*NSEQ*HD;  // [8192][768]

  // fused prepass: cvt x + transpose/cvt both weights (one launch)
  prepass<<<6720, 256, 0, stream>>>(x, xh, w_qkv, wqT, w_proj, wpT);

  // QKV GEMM + bias + RoPE + scatter (q,k natural; v transposed+sigma-perm)
  gemm_qkv<<<dim3(NQKV/128, MROWS/128), 256, 0, stream>>>(
      xh, wqT, b_qkv, qh, kh, vth, EMB);

  // flash attention (async-staged pipelined K/V, exp2+pkrtz softmax, setprio)
  attn_mfma32<<<dim3(NSEQ/128, BATCH*NH), 256, 0, stream>>>(qh, kh, vth, aoh);

  // proj GEMM -> f32 out (128x64 tiles, 768 blocks = 3/CU)
  gemm_proj<<<dim3(EMB/64, MROWS/128), 256, 0, stream>>>(
      aoh, wpT, b_proj, out, EMB);
}

// Round 9
// 187.525 us; speedup vs baseline: 1.0713x; 1.0713x over previous
//
#include <hip/hip_runtime.h>
#include <math.h>

#define NH 12
#define HD 64
#define NSEQ 1024
#define BATCH 8
#define EMB 768
#define NQKV 2304
#define MROWS 8192   // B*N

typedef _Float16 half8 __attribute__((ext_vector_type(8)));
typedef _Float16 half4 __attribute__((ext_vector_type(4)));
typedef _Float16 half2v __attribute__((ext_vector_type(2)));
typedef __fp16 fp16x2 __attribute__((ext_vector_type(2)));   // cvt_pkrtz ret type
typedef float f32x4 __attribute__((ext_vector_type(4)));
typedef float f32x16 __attribute__((ext_vector_type(16)));
typedef unsigned int u32;

#define MFMA16(a,b,c) __builtin_amdgcn_mfma_f32_16x16x32_f16(a, b, c, 0, 0, 0)
#define MFMA32(a,b,c) __builtin_amdgcn_mfma_f32_32x32x16_f16(a, b, c, 0, 0, 0)

// q pre-scale folds softmax's log2(e): 0.125 * 1.4426950408889634
#define QSCALE 0.18033688011112043f
// exp bias: 4 * log2(e)  (p = 2^(s*0.125*log2e - 5.7708) == e^(s*0.125 - 4))
#define EXPB 5.770780163555856f

// async global->LDS, 16B per lane; LDS dest is wave-uniform base + lane*16.
#define ASYNC16(g, l)                                                          \
  __builtin_amdgcn_global_load_lds(                                            \
      (const __attribute__((address_space(1))) unsigned int*)(g),              \
      (__attribute__((address_space(3))) unsigned int*)(l), 16, 0, 0)

// ---------------------------------------------------------------------------
// Fused prepass: [0,6144) f32->f16 convert of x; [6144,6576) transpose+cvt
// w_qkv; [6576,6720) transpose+cvt w_proj. One launch.
// ---------------------------------------------------------------------------
__device__ __forceinline__ void transpose_tile(const float* __restrict__ in,
                                               _Float16* __restrict__ out,
                                               int R, int C, int bx, int by,
                                               _Float16 (*T)[72]) {
  const int tr = by * 64, tc = bx * 64;
  const int r = threadIdx.x >> 2, s = threadIdx.x & 3;
  const float* src = in + (size_t)(tr + r) * C + tc + s * 16;
  _Float16* dst = &T[r][s * 16];
  #pragma unroll
  for (int i = 0; i < 4; ++i) {
    float4 v = ((const float4*)src)[i];
    dst[4*i+0] = (_Float16)v.x; dst[4*i+1] = (_Float16)v.y;
    dst[4*i+2] = (_Float16)v.z; dst[4*i+3] = (_Float16)v.w;
  }
  __syncthreads();
  alignas(16) _Float16 tmp[16];
  #pragma unroll
  for (int j = 0; j < 16; ++j) tmp[j] = T[s * 16 + j][r];
  half8* o = (half8*)(out + (size_t)(tc + r) * R + tr + s * 16);
  o[0] = *(half8*)&tmp[0];
  o[1] = *(half8*)&tmp[8];
}

__global__ __launch_bounds__(256) void prepass(const float* __restrict__ x,
                                               _Float16* __restrict__ xh,
                                               const float* __restrict__ wq,
                                               _Float16* __restrict__ wqT,
                                               const float* __restrict__ wp,
                                               _Float16* __restrict__ wpT) {
  __shared__ _Float16 T[64][72];
  const int bid = blockIdx.x;
  if (bid < 6144) {
    int i = bid * 256 + threadIdx.x;            // n4 = 8192*768/4 = 1572864
    float4 v = ((const float4*)x)[i];
    half4 h = { (_Float16)v.x, (_Float16)v.y, (_Float16)v.z, (_Float16)v.w };
    ((half4*)xh)[i] = h;
  } else if (bid < 6576) {
    int idx = bid - 6144;                        // 36 x 12
    transpose_tile(wq, wqT, EMB, NQKV, idx % 36, idx / 36, T);
  } else {
    int idx = bid - 6576;                        // 12 x 12
    transpose_tile(wp, wpT, EMB, EMB, idx % 12, idx / 12, T);
  }
}

// XCD-aware bijective tile remap (nwg % 8 == 0): default dispatch
// round-robins flat ids over the 8 XCDs; remapping to (f%8)*(nwg/8) + f/8
// gives each XCD a contiguous tile range -> shared operand panels stay
// L2-resident per XCD. (R4: QKV FETCH 63.7->34.7 MB.)
__device__ __forceinline__ int xcd_remap() {
  const int flat = blockIdx.y * gridDim.x + blockIdx.x;
  const int q = (gridDim.x * gridDim.y) >> 3;
  return (flat & 7) * q + (flat >> 3);
}

// ---------------------------------------------------------------------------
// QKV GEMM, 128x128 tile, 256 threads (4 waves, 2x2), BK=32, dbuf.
// EXACT R5 SCHEDULE (measured floor 55 µs across seven variants).
// ASYNC-STAGED (global_load_lds width 16) pipelined K-loop. LDS dest LINEAR;
// XOR image LDS[r][s] = G[r][s ^ ((r>>1)&3)] via PRE-SWIZZLED global source
// seg; frag reads conflict-free (xq = quad ^ ((l15>>1)&3)).
// A [M][K] k-contig, BT [N][K] k-contig.
// Epilogue: bias + RoPE (pos = head!) + q*QSCALE (0.125*log2e, folding
//           softmax's exp2); q,k [bh][n][d] f16, v TRANSPOSED [bh][d][n]
//           f16 with keys sigma-permuted (bits 2<->3) so attention needs
//           no P lane-exchange.
// ---------------------------------------------------------------------------
__global__ __launch_bounds__(256) void gemm_qkv(const _Float16* __restrict__ A,
                                                const _Float16* __restrict__ BT,
                                                const float* __restrict__ bias,
                                                _Float16* __restrict__ qo,
                                                _Float16* __restrict__ ko,
                                                _Float16* __restrict__ vo,
                                                int K) {
  const int BUFH = 128 * 32;
  __shared__ __align__(16) _Float16 As[2 * 128 * 32];   // [buf][m][k] pitch 32
  __shared__ __align__(16) _Float16 Bs[2 * 128 * 32];   // [buf][n][k] pitch 32
  const int tid = threadIdx.x;
  const int lane = tid & 63, wave = tid >> 6;
  const int quad = lane >> 4, l15 = lane & 15;
  const int wm = (wave >> 1) * 64, wn = (wave & 1) * 64;
  const int nf = xcd_remap();
  const int row0 = (nf / gridDim.x) * 128, col0 = (nf % gridDim.x) * 128;

  // staging: wave w covers rows [w*32, w*32+32) of A and B, two 16-row
  // batches of 1024B each.  Lane l -> dest row l>>2, dest seg l&3 (linear);
  // source seg is XOR-swizzled so the LDS image matches the frag reads.
  const int srow = lane >> 2;
  const int sseg = (lane & 3) ^ ((srow >> 1) & 3);   // pre-swizzled src seg
  const _Float16* gA = A + (size_t)(row0 + wave*32 + srow) * K + sseg * 8;
  const _Float16* gB = BT + (size_t)(col0 + wave*32 + srow) * K + sseg * 8;
  _Float16* lA = As + (wave * 32) * 32;              // wave-uniform LDS base
  _Float16* lB = Bs + (wave * 32) * 32;

  // frag-read swizzled col (lane constant: (row>>1)&3 == (l15>>1)&3)
  const int xq = (quad ^ ((l15 >> 1) & 3)) * 8;

  f32x4 acc[4][4];
  #pragma unroll
  for (int i = 0; i < 4; ++i)
    #pragma unroll
    for (int j = 0; j < 4; ++j) {
      f32x4 z = {0.f, 0.f, 0.f, 0.f};
      acc[i][j] = z;
    }

  // prologue: stage k0=0 into buf 0 (4 x global_load_lds_dwordx4 per wave)
  ASYNC16(gA,          lA);
  ASYNC16(gA + 16 * K, lA + 16*32);
  ASYNC16(gB,          lB);
  ASYNC16(gB + 16 * K, lB + 16*32);
  __syncthreads();

  int buf = 0;
  for (int k0 = 0; k0 < K; k0 += 32) {
    if (k0 + 32 < K) {               // issue next-stage direct-to-LDS loads
      const int nb = (buf ^ 1) * BUFH;        //  (latency hidden behind MFMAs)
      ASYNC16(gA + k0 + 32,          lA + nb);
      ASYNC16(gA + k0 + 32 + 16 * K, lA + nb + 16*32);
      ASYNC16(gB + k0 + 32,          lB + nb);
      ASYNC16(gB + k0 + 32 + 16 * K, lB + nb + 16*32);
    }
    const _Float16* Ab = As + buf * BUFH;
    const _Float16* Bb = Bs + buf * BUFH;
    half8 af[4], bf[4];
    #pragma unroll
    for (int mt = 0; mt < 4; ++mt)
      af[mt] = *(const half8*)(Ab + (wm + mt*16 + l15) * 32 + xq);
    #pragma unroll
    for (int nt = 0; nt < 4; ++nt)
      bf[nt] = *(const half8*)(Bb + (wn + nt*16 + l15) * 32 + xq);
    #pragma unroll
    for (int mt = 0; mt < 4; ++mt)
      #pragma unroll
      for (int nt = 0; nt < 4; ++nt)
        acc[mt][nt] = MFMA16(af[mt], bf[nt], acc[mt][nt]);
    __syncthreads();                 // drains vmcnt -> buf^1 ready
    buf ^= 1;
  }

  float bcol[4];
  #pragma unroll
  for (int nt = 0; nt < 4; ++nt)
    bcol[nt] = bias[col0 + wn + nt*16 + l15];

  const int ch = col0 + wn;           // multiple of 64 -> single (t, h)
  const int tt = ch / EMB;
  const int hh = (ch % EMB) >> 6;
  float cs[2], sn[2];
  if (tt < 2) {
    #pragma unroll
    for (int j = 0; j < 2; ++j) {
      float fi = (float)(j*16 + l15);
      float ang = (float)hh * expf(-0.28782313662425574f * fi);
      sincosf(ang, &sn[j], &cs[j]);
    }
  }
  #pragma unroll
  for (int mt = 0; mt < 4; ++mt) {
    int m0 = row0 + wm + mt*16 + quad*4;
    int b = m0 >> 10, n0 = m0 & 1023;
    size_t bh = (size_t)(b * NH + hh);
    if (tt == 2) {
      // sigma-permuted key position (swap bits 2<->3; n0 multiple of 4)
      int np = (n0 & ~12) | ((n0 & 4) << 1) | ((n0 & 8) >> 1);
      #pragma unroll
      for (int nt = 0; nt < 4; ++nt) {
        int d = nt*16 + l15;
        half4 pk;
        #pragma unroll
        for (int r = 0; r < 4; ++r)
          pk[r] = (_Float16)(acc[mt][nt][r] + bcol[nt]);
        *(half4*)(vo + (bh * HD + d) * NSEQ + np) = pk;
      }
    } else {
      _Float16* dst = (tt == 0) ? qo : ko;
      const float sc = (tt == 0) ? QSCALE : 1.0f;
      #pragma unroll
      for (int j = 0; j < 2; ++j) {
        #pragma unroll
        for (int r = 0; r < 4; ++r) {
          float lo = acc[mt][j][r]     + bcol[j];
          float hi = acc[mt][j + 2][r] + bcol[j + 2];
          float nlo = (lo * cs[j] - hi * sn[j]) * sc;
          float nhi = (hi * cs[j] + lo * sn[j]) * sc;
          size_t rowoff = (bh * NSEQ + (size_t)(n0 + r)) * HD;
          dst[rowoff + j*16 + l15]      = (_Float16)nlo;
          dst[rowoff + j*16 + l15 + 32] = (_Float16)nhi;
        }
      }
    }
  }
}

// ---------------------------------------------------------------------------
// Proj GEMM, 128x64 tile, BK=64 (12 K-steps vs 24): doubles MFMA-per-barrier
// (8->16) and HALVES the vmcnt-drain barrier count -- the structural stall
// of this 2-phase schedule -- while 48KB LDS keeps 3 blocks/CU.
// Staging: lane -> (row=l>>3, seg=l&7); A 4 batches (rows +0/8/16/24),
// B 2 batches (rows +0/8); dest LINEAR (= base + lane*16B); source seg
// pre-swizzled seg^(row&7) (row&7 invariant across batches) so the image is
// LDS[r][s] = G[r][s ^ (r&7)]. Frag slot (kk*4+quad)^(l15&7): within each
// 16-lane phase (one quad) every slot is hit by exactly 2 lanes (rows r,
// r+8 -> same bank, diff addr) = 2-way = free. out f32 = acc + bias.
// ---------------------------------------------------------------------------
__global__ __launch_bounds__(256) void gemm_proj(const _Float16* __restrict__ A,
                                                 const _Float16* __restrict__ BT,
                                                 const float* __restrict__ bias,
                                                 float* __restrict__ outf,
                                                 int K) {
  const int ABUF = 128 * 64, BBUF = 64 * 64;        // halves per buffer
  __shared__ __align__(16) _Float16 As[2 * ABUF];   // 32 KB, [buf][m][k] p64
  __shared__ __align__(16) _Float16 Bs[2 * BBUF];   // 16 KB, [buf][n][k] p64
  const int tid = threadIdx.x;
  const int lane = tid & 63, wave = tid >> 6;
  const int quad = lane >> 4, l15 = lane & 15;
  const int wm = (wave >> 1) * 64, wn = (wave & 1) * 32;
  const int nf = xcd_remap();
  const int row0 = (nf / gridDim.x) * 128, col0 = (nf % gridDim.x) * 64;

  const int srow = lane >> 3;                        // 0..7
  const int sseg = (lane & 7) ^ (srow & 7);          // pre-swizzled source
  const _Float16* gA = A  + (size_t)(row0 + wave*32 + srow) * K + sseg * 8;
  const _Float16* gB = BT + (size_t)(col0 + wave*16 + srow) * K + sseg * 8;
  _Float16* lA = As + (wave * 32) * 64;              // linear async dests
  _Float16* lB = Bs + (wave * 16) * 64;

  f32x4 acc[4][2];
  #pragma unroll
  for (int i = 0; i < 4; ++i)
    #pragma unroll
    for (int j = 0; j < 2; ++j) {
      f32x4 z = {0.f, 0.f, 0.f, 0.f};
      acc[i][j] = z;
    }

  // prologue: stage tile 0 into buf 0 (A: 4 batches; B: 2 batches)
  ASYNC16(gA,          lA);
  ASYNC16(gA +  8 * K, lA +  8*64);
  ASYNC16(gA + 16 * K, lA + 16*64);
  ASYNC16(gA + 24 * K, lA + 24*64);
  ASYNC16(gB,          lB);
  ASYNC16(gB +  8 * K, lB +  8*64);
  __syncthreads();

  int buf = 0;
  for (int k0 = 0; k0 < K; k0 += 64) {
    if (k0 + 64 < K) {
      const int na = (buf ^ 1) * ABUF, nb = (buf ^ 1) * BBUF;
      ASYNC16(gA + k0 + 64,          lA + na);
      ASYNC16(gA + k0 + 64 +  8 * K, lA + na +  8*64);
      ASYNC16(gA + k0 + 64 + 16 * K, lA + na + 16*64);
      ASYNC16(gA + k0 + 64 + 24 * K, lA + na + 24*64);
      ASYNC16(gB + k0 + 64,          lB + nb);
      ASYNC16(gB + k0 + 64 +  8 * K, lB + nb +  8*64);
    }
    const _Float16* Ab = As + buf * ABUF;
    const _Float16* Bb = Bs + buf * BBUF;
    #pragma unroll
    for (int kk = 0; kk < 2; ++kk) {
      const int x = ((kk*4 + quad) ^ (l15 & 7)) * 8;
      half8 af[4], bf[2];
      #pragma unroll
      for (int mt = 0; mt < 4; ++mt)
        af[mt] = *(const half8*)(Ab + (wm + mt*16 + l15) * 64 + x);
      #pragma unroll
      for (int nt = 0; nt < 2; ++nt)
        bf[nt] = *(const half8*)(Bb + (wn + nt*16 + l15) * 64 + x);
      #pragma unroll
      for (int mt = 0; mt < 4; ++mt)
        #pragma unroll
        for (int nt = 0; nt < 2; ++nt)
          acc[mt][nt] = MFMA16(af[mt], bf[nt], acc[mt][nt]);
    }
    __syncthreads();
    buf ^= 1;
  }

  float bcol[2];
  #pragma unroll
  for (int nt = 0; nt < 2; ++nt)
    bcol[nt] = bias[col0 + wn + nt*16 + l15];
  #pragma unroll
  for (int mt = 0; mt < 4; ++mt) {
    int m0 = row0 + wm + mt*16 + quad*4;
    #pragma unroll
    for (int nt = 0; nt < 2; ++nt)
      #pragma unroll
      for (int r = 0; r < 4; ++r)
        outf[(size_t)(m0 + r) * EMB + col0 + wn + nt*16 + l15] =
            acc[mt][nt][r] + bcol[nt];
  }
}

// ---------------------------------------------------------------------------
// f16 MFMA flash attention, 32x32x16, ASYNC-STAGED pipelined K/V chunks:
// global_load_lds (width 16) issues next chunk's loads into buf^1 at loop
// top; the bottom __syncthreads drains vmcnt. LDS dest LINEAR; the image
// LDS[r][s] = G[r][s ^ (r&7)] comes from PRE-SWIZZLING the global source
// segment (seg' = sseg8 ^ (srow8&7)). Static softmax p = 2^(s - EXPB)
// (q pre-scaled by 0.125*log2e; shift cancels in normalization), packed to
// f16 via cvt_pkrtz; denominator accumulated in TWO independent chains
// (halves the 16-deep dependent fp-add chain on the contended VALU pipe).
// V keys sigma-permuted by the QKV epilogue so S^T C-regs ARE the PV
// B-fragment. s_setprio(1) wraps both MFMA clusters (T5). Block = 256 thr
// (4 waves) = 128 queries; chunk = 64 keys shared by waves. XCD remap: each
// XCD owns 12 complete bh groups. q,k: [bh][n][d] f16. vt: [bh][d][key_sigma]
// f16. Output ao: [B*N][EMB] f16.
// ---------------------------------------------------------------------------
__global__ __launch_bounds__(256) void attn_mfma32(const _Float16* __restrict__ q,
                                                   const _Float16* __restrict__ k,
                                                   const _Float16* __restrict__ vt,
                                                   _Float16* __restrict__ ao) {
  const int BUFH = 64 * 64;
  __shared__ __align__(16) _Float16 Ks[2 * 64 * 64];   // [buf][key][slot*8]
  __shared__ __align__(16) _Float16 Vs[2 * 64 * 64];   // [buf][d][slot*8]
  const int tid = threadIdx.x;
  const int lane = tid & 63, wave = tid >> 6;
  const int l31 = lane & 31, hi = lane >> 5;
  const int nf = xcd_remap();                    // grid (8, 96), 768 % 8 == 0
  const int bh = nf >> 3;
  const int qrow = (nf & 7) * 128 + wave * 32 + l31;     // global query idx
  const size_t base = (size_t)bh * NSEQ * HD;

  // Q fragments (B-operand: [n=query][k=d]) in registers for all chunks
  const _Float16* qp = q + base + (size_t)qrow * HD + hi * 8;
  half8 qf[4];
  #pragma unroll
  for (int kh = 0; kh < 4; ++kh)
    qf[kh] = *(const half8*)(qp + kh * 16);

  // staging: wave covers rows wave*16..+15 (batches srow8, srow8+8).
  // Lane l -> LINEAR dest (row l>>3, seg l&7 from wave base); global source
  // seg pre-swizzled so LDS image is LDS[r][s] = G[r][s ^ (r&7)].
  const int srow8 = lane >> 3;                    // 0..7
  const int sseg8 = lane & 7;
  const int wseg8 = sseg8 ^ (srow8 & 7);          // pre-swizzled src seg
  const _Float16* kg = k + base + (size_t)(wave*16 + srow8) * HD + wseg8 * 8;
  const _Float16* vg = vt + (size_t)bh * HD * NSEQ
                       + (size_t)(wave*16 + srow8) * NSEQ + wseg8 * 8;
  _Float16* uK = Ks + (wave * 16) * 64;           // wave-uniform LDS bases
  _Float16* uV = Vs + (wave * 16) * 64;

  // frag-read swizzled offsets (halves): slot = (kh*2+hi) ^ (l31&7)
  int xofs[4];
  #pragma unroll
  for (int kh = 0; kh < 4; ++kh)
    xofs[kh] = ((kh*2 + hi) ^ (l31 & 7)) * 8;

  f32x16 O[2];
  #pragma unroll
  for (int dt = 0; dt < 2; ++dt)
    #pragma unroll
    for (int r = 0; r < 16; ++r) O[dt][r] = 0.f;
  float l = 0.f;

  // prologue: stage chunk 0 into buf 0 (4 x global_load_lds_dwordx4)
  ASYNC16(kg,              uK);
  ASYNC16(kg + 8 * HD,     uK + 8*64);
  ASYNC16(vg,              uV);
  ASYNC16(vg + 8 * NSEQ,   uV + 8*64);
  __syncthreads();

  int buf = 0;
  for (int c0 = 0; c0 < NSEQ; c0 += 64) {
    if (c0 + 64 < NSEQ) {          // next chunk's loads, hidden behind compute
      const int nb = (buf ^ 1) * BUFH;
      const _Float16* kc = kg + (size_t)(c0 + 64) * HD;
      ASYNC16(kc,                  uK + nb);
      ASYNC16(kc + 8 * HD,         uK + nb + 8*64);
      ASYNC16(vg + c0 + 64,        uV + nb);
      ASYNC16(vg + 8*NSEQ + c0 + 64, uV + nb + 8*64);
    }
    const _Float16* Kb = Ks + buf * BUFH;
    const _Float16* Vb = Vs + buf * BUFH;

    // ---- S^T = K Q^T : 2 key-tiles of 32, K=16 per MFMA over D=64 ----
    f32x16 ct[2];
    __builtin_amdgcn_s_setprio(1);
    #pragma unroll
    for (int kt = 0; kt < 2; ++kt) {
      #pragma unroll
      for (int r = 0; r < 16; ++r) ct[kt][r] = 0.f;
      #pragma unroll
      for (int kh = 0; kh < 4; ++kh) {
        half8 kf = *(const half8*)(Kb + (kt*32 + l31) * 64 + xofs[kh]);
        ct[kt] = MFMA32(kf, qf[kh], ct[kt]);
      }
    }
    __builtin_amdgcn_s_setprio(0);

    // ---- static softmax: p = 2^(s - EXPB); two independent l-chains ----
    union { half2v v; fp16x2 f; int i; } ph2[16];
    float rs0 = 0.f, rs1 = 0.f;
    #pragma unroll
    for (int rp = 0; rp < 8; ++rp) {
      float a0 = __builtin_amdgcn_exp2f(ct[0][2*rp]     - EXPB);
      float a1 = __builtin_amdgcn_exp2f(ct[0][2*rp + 1] - EXPB);
      float b0 = __builtin_amdgcn_exp2f(ct[1][2*rp]     - EXPB);
      float b1 = __builtin_amdgcn_exp2f(ct[1][2*rp + 1] - EXPB);
      rs0 += a0 + a1;
      rs1 += b0 + b1;
      ph2[rp].f     = __builtin_amdgcn_cvt_pkrtz(a0, a1);
      ph2[8 + rp].f = __builtin_amdgcn_cvt_pkrtz(b0, b1);
    }
    l += rs0 + rs1;

    // ---- O^T += V^T P^T : P^T B-frag = C-regs directly (V sigma-perm) ----
    __builtin_amdgcn_s_setprio(1);
    #pragma unroll
    for (int kh = 0; kh < 4; ++kh) {
      const int kt = kh >> 1;
      const int iA = kt*8 + (kh & 1)*4;
      union { half8 h; int d[4]; } pf;
      pf.d[0] = ph2[iA].i;     pf.d[1] = ph2[iA + 1].i;
      pf.d[2] = ph2[iA + 2].i; pf.d[3] = ph2[iA + 3].i;
      #pragma unroll
      for (int dt = 0; dt < 2; ++dt) {
        half8 vf = *(const half8*)(Vb + (dt*32 + l31) * 64 + xofs[kh]);
        O[dt] = MFMA32(vf, pf.h, O[dt]);
      }
    }
    __builtin_amdgcn_s_setprio(0);

    __syncthreads();               // drains vmcnt -> buf^1 ready
    buf ^= 1;
  }

  // each lane's l covers its 32 score regs; xor-32 partner holds the rest
  l += __shfl_xor(l, 32);

  // ---- write O^T (col=query=lane&31, rows=d) to ao[B*N][EMB] ----
  const int b = bh / NH, hh = bh % NH;
  const float inv = 1.0f / l;
  _Float16* orow = ao + (size_t)(b * NSEQ + qrow) * EMB + hh * HD;
  #pragma unroll
  for (int dt = 0; dt < 2; ++dt)
    #pragma unroll
    for (int t = 0; t < 4; ++t) {
      int d0 = dt*32 + 8*t + 4*hi;          // rows (r&3)+8*(r>>2)+4*hi
      half4 o4;
      #pragma unroll
      for (int j = 0; j < 4; ++j)
        o4[j] = (_Float16)(O[dt][4*t + j] * inv);
      *(half4*)(orow + d0) = o4;
    }
}

// ---------------------------------------------------------------------------
extern "C" void kernel_launch(void* const* d_in, const int* in_sizes, int n_in,
                              void* d_out, int out_size, void* d_ws, size_t ws_size,
                              hipStream_t stream) {
  const float* x      = (const float*)d_in[0];
  const float* w_qkv  = (const float*)d_in[1];
  const float* b_qkv  = (const float*)d_in[2];
  const float* w_proj = (const float*)d_in[3];
  const float* b_proj = (const float*)d_in[4];
  float* out = (float*)d_out;

  _Float16* xh  = (_Float16*)d_ws;                 // [8192][768]
  _Float16* wqT = xh  + (size_t)MROWS * EMB;       // [2304][768]
  _Float16* wpT = wqT + (size_t)NQKV * EMB;        // [768][768]
  _Float16* qh  = wpT + (size_t)EMB * EMB;         // [96][1024][64]
  _Float16* kh  = qh  + (size_t)BATCH*NH*NSEQ*HD;
  _Float16* vth = kh  + (size_t)BATCH*NH*NSEQ*HD;  // [96][64][1024] sigma-perm
  _Float16* aoh = vth + (size_t)BATCH*NH*NSEQ*HD;  // [8192][768]

  // fused prepass: cvt x + transpose/cvt both weights (one launch)
  prepass<<<6720, 256, 0, stream>>>(x, xh, w_qkv, wqT, w_proj, wpT);

  // QKV GEMM + bias + RoPE + scatter (q,k natural; v transposed+sigma-perm)
  gemm_qkv<<<dim3(NQKV/128, MROWS/128), 256, 0, stream>>>(
      xh, wqT, b_qkv, qh, kh, vth, EMB);

  // flash attention (async-staged pipelined K/V, exp2+pkrtz softmax, setprio)
  attn_mfma32<<<dim3(NSEQ/128, BATCH*NH), 256, 0, stream>>>(qh, kh, vth, aoh);

  // proj GEMM -> f32 out (128x64 tiles, BK=64, 768 blocks = 3/CU)
  gemm_proj<<<dim3(EMB/64, MROWS/128), 256, 0, stream>>>(
      aoh, wpT, b_proj, out, EMB);
}